// Round 4
// baseline (147.205 us; speedup 1.0000x reference)
//
#include <hip/hip_runtime.h>

// EdgeAttention round 12 (resubmit after broker timeout): proj0_dots LDS-conflict
// + epilogue-overlap polish.
// Evidence r11: counted-vmcnt pipeline -10.3us (latency theory confirmed).
// Remaining model: (a) bf-frag scalar reads were a 4-way bank conflict
// (row stride 1KB == 0 mod 32 banks) -> fix by rotating the DMA *global*
// source px by 8*(ch>>3) and reading with the same rotation (rule #21):
// bank = (ln + 8*quad) mod 32 = uniform 2-way = free.
// (b) epilogue u1/u2/u3 staging (42KB, reg loads + ds_writes + 2 barriers)
// moved to prologue global_load_lds into a dedicated LDS region (96K+42K
// < 160K): u-DMAs are oldest in the vmcnt queue, complete under iter 0-1,
// published by the loop's own barriers; epilogue reads S directly with a
// px-rotation chunk swizzle (slot = px*32 + (s+px)&31) replacing SPITCH.
// proj_small + softmax4 unchanged (validated).

#define CCH 256
#define WPITCH 40   // proj_small LDS pitch (r8, validated)

typedef __attribute__((ext_vector_type(8))) short short8;
typedef __attribute__((ext_vector_type(4))) short short4_;
typedef __attribute__((ext_vector_type(4))) float float4_;

__device__ inline short f2bf(float x) {
    union { float f; unsigned u; } c; c.f = x;
    unsigned u = c.u + 0x7FFFu + ((c.u >> 16) & 1u);
    return (short)(u >> 16);
}
__device__ inline float bf2f(short b) {
    union { unsigned u; float f; } c; c.u = ((unsigned)(unsigned short)b) << 16;
    return c.f;
}

__device__ inline void dma16(const void* g, void* l) {
    __builtin_amdgcn_global_load_lds(
        (const __attribute__((address_space(1))) void*)g,
        (__attribute__((address_space(3))) void*)l, 16, 0, 0);
}

// ---------- proj_small: scales 1..3 -> pixel-major unit vectors (r8, validated) ------
// Blocks 272..303 instead pack W0 fp32 -> bf16 fragment-linear for proj0_dots' DMA.
__global__ __launch_bounds__(256) void proj_small(
    const float* __restrict__ f1, const float* __restrict__ f2,
    const float* __restrict__ f3,
    const float* __restrict__ w0, const float* __restrict__ w1,
    const float* __restrict__ w2, const float* __restrict__ w3,
    const float* __restrict__ b1, const float* __restrict__ b2,
    const float* __restrict__ b3,
    short* __restrict__ u1, short* __restrict__ u2, short* __restrict__ u3,
    short* __restrict__ wp)
{
    __shared__ __align__(16) short Wt[256 * WPITCH];
    __shared__ __align__(16) short Ft[64 * WPITCH];

    const int blk = blockIdx.x;
    const int t = threadIdx.x;

    if (blk >= 272) {   // ---- W0 pack: pos = ks*8192 + mt*512 + (quad*16+ln)*8 + e ----
        int id = (blk - 272) * 256 + t;      // 0..8191 short8s
        int ks = id >> 10;
        int rest = id & 1023;
        int mt = rest >> 6;
        int fl = rest & 63;
        int ln = fl & 15, qd = fl >> 4;
        const float* src = w0 + (size_t)(mt * 16 + ln) * CCH + ks * 32 + qd * 8;
        short8 v;
#pragma unroll
        for (int j = 0; j < 8; ++j) v[j] = f2bf(src[j]);
        *(short8*)(wp + (size_t)id * 8) = v;
        return;
    }

    int b, tile, L;
    const float* F; const float* Wg; const float* bias; short* U;
    if (blk < 200)      { int r = blk;       b = r / 25; tile = r % 25; L = 1600; F = f1; Wg = w1; bias = b1; U = u1; }
    else if (blk < 256) { int r = blk - 200; b = r / 7;  tile = r % 7;  L = 400;  F = f2; Wg = w2; bias = b2; U = u2; }
    else                { int r = blk - 256; b = r / 2;  tile = r % 2;  L = 100;  F = f3; Wg = w3; bias = b3; U = u3; }

    const int lane = t & 63;
    const int wav  = t >> 6;
    const int ln   = lane & 15;
    const int quad = lane >> 4;
    const int pixbase = tile * 64;
    const float* Fb = F + (size_t)b * CCH * L;

    const int wo = t >> 2;
    const int wk = (t & 3) * 8;
    const int fpix = t & 63;
    const int fchunk = t >> 6;
    const int gpix0 = pixbase + fpix;
    const bool pin = gpix0 < L;
    const int gl0 = pin ? gpix0 : 0;

    float4_ wbufA[4], wbufB[4];
    float fbuf[8];
    auto loadW = [&](int ks) {
#pragma unroll
        for (int p = 0; p < 4; ++p) {
            const float* srcp = Wg + (size_t)(p * 64 + wo) * CCH + ks * 32 + wk;
            wbufA[p] = *(const float4_*)srcp;
            wbufB[p] = *(const float4_*)(srcp + 4);
        }
    };
    auto loadF = [&](int ks) {
        const float* fs = Fb + (size_t)(ks * 32 + fchunk * 8) * L + gl0;
#pragma unroll
        for (int j = 0; j < 8; ++j) fbuf[j] = fs[(size_t)j * L];
    };

    float4_ acc[16];
#pragma unroll
    for (int i = 0; i < 16; ++i) acc[i] = (float4_){0.f, 0.f, 0.f, 0.f};

    loadW(0); loadF(0);
    for (int ks = 0; ks < 8; ++ks) {
        __syncthreads();
#pragma unroll
        for (int p = 0; p < 4; ++p) {
            short8 v;
#pragma unroll
            for (int e = 0; e < 4; ++e) { v[e] = f2bf(wbufA[p][e]); v[e + 4] = f2bf(wbufB[p][e]); }
            *(short8*)(&Wt[(p * 64 + wo) * WPITCH + wk]) = v;
        }
        {
            short8 v;
#pragma unroll
            for (int j = 0; j < 8; ++j) v[j] = pin ? f2bf(fbuf[j]) : (short)0;
            *(short8*)(&Ft[fpix * WPITCH + fchunk * 8]) = v;
        }
        __syncthreads();
        const int ksn = (ks + 1) & 7;
        loadW(ksn); loadF(ksn);

        short8 bfrag = *(const short8*)(&Ft[(wav * 16 + ln) * WPITCH + quad * 8]);
#pragma unroll
        for (int mt = 0; mt < 16; ++mt) {
            short8 afrag = *(const short8*)(&Wt[(mt * 16 + ln) * WPITCH + quad * 8]);
            acc[mt] = __builtin_amdgcn_mfma_f32_16x16x32_bf16(afrag, bfrag, acc[mt], 0, 0, 0);
        }
    }

    float ss = 0.f;
#pragma unroll
    for (int mt = 0; mt < 16; ++mt) {
        float4_ bv = *(const float4_*)(bias + mt * 16 + quad * 4);
#pragma unroll
        for (int r = 0; r < 4; ++r) { float v = acc[mt][r] + bv[r]; acc[mt][r] = v; ss += v * v; }
    }
    ss += __shfl_xor(ss, 16);
    ss += __shfl_xor(ss, 32);
    const float inv = 1.f / sqrtf(fmaxf(ss, 1e-24f));

    const int gpixw = pixbase + wav * 16 + ln;
    if (gpixw < L) {
        short* dst = U + ((size_t)b * L + gpixw) * CCH;
#pragma unroll
        for (int mt = 0; mt < 16; ++mt) {
            short4_ v;
#pragma unroll
            for (int r = 0; r < 4; ++r) v[r] = f2bf(acc[mt][r] * inv);
            *(short4_*)(dst + mt * 16 + quad * 4) = v;
        }
    }
}

// ---------- proj0_dots v5: rotated-swizzle F, prologue u-DMA, lean epilogue ------
// Block = (cell c = blockIdx.x in 0..24, b = blockIdx.y). Tile = fine rows
// [16R,16R+16), cols [16C,16C+16), R = c/5, C = c%5. 8 waves; wave w owns fine
// rows {2w, 2w+1}: pxA = 32w+ln (row 2w), pxB = pxA+16 (row 2w+1).
// F LDS: float slot i of ch-row k holds global px p = (i - 8*(k>>3)) & 255
//   -> read bank (ln + 8*quad) mod 32 = uniform 2-way (free).
// S LDS: 16B chunk (px, s) lives at slot px*32 + ((s+px)&31) -> fine/coarse
//   dot reads spread over banks (replaces r10's SPITCH pad, DMA-compatible).
__global__ __launch_bounds__(512, 2) void proj0_dots(
    const float* __restrict__ F, const short* __restrict__ wp,
    const float* __restrict__ bias,
    const short* __restrict__ u1, const short* __restrict__ u2,
    const short* __restrict__ u3,
    float* __restrict__ partial)
{
    extern __shared__ __align__(16) char smem[];  // 141568 B dynamic
    short* Wb0 = (short*)smem;                    // 16 KB bf16 W slice, buf 0
    short* Wb1 = (short*)(smem + 16384);          // buf 1
    float* Fb0 = (float*)(smem + 32768);          // 32 KB fp32 F slice [32ch][256px]
    float* Fb1 = (float*)(smem + 65536);          // buf 1 (ends at 98304)
    short* S1c = (short*)(smem + 98304);          // u1: 64 px * 512 B = 32768
    short* S2c = (short*)(smem + 131072);         // u2: 16 px * 512 B =  8192
    short* S3c = (short*)(smem + 139264);         // u3:  4 px * 512 B =  2048
    float* redF = (float*)(smem + 141312);        // [8][3]
    float* redC = (float*)(smem + 141312 + 96);   // [9]

    const int c  = blockIdx.x;         // 0..24
    const int b  = blockIdx.y;
    const int R  = c / 5, C = c - R * 5;
    const int t  = threadIdx.x;
    const int lane = t & 63;
    const int wav  = t >> 6;           // 0..7
    const int ln   = lane & 15;
    const int quad = lane >> 4;
    const float* Fbase = F + (size_t)b * CCH * 6400;

    auto dmaW = [&](int ks, int buf) {             // 2 instr/wave (16 KB total)
        short* Wb = buf ? Wb1 : Wb0;
#pragma unroll
        for (int m = 0; m < 2; ++m) {
            const int k = wav * 2 + m;                      // 0..15
            dma16(wp + (size_t)ks * 8192 + k * 512 + lane * 8, Wb + k * 512);
        }
    };
    auto dmaF = [&](int ks, int buf) {             // 4 instr/wave (32 KB total)
        float* Fb = buf ? Fb1 : Fb0;
#pragma unroll
        for (int m = 0; m < 4; ++m) {
            const int k = wav * 4 + m;                      // channel 0..31
            const int p0 = (lane * 4 - (k >> 3) * 8) & 255; // rotated source px
            const int gpx = (16 * R + (p0 >> 4)) * 80 + 16 * C + (p0 & 15);
            dma16(Fbase + (size_t)(ks * 32 + k) * 6400 + gpx, Fb + k * 256);
        }
    };
    // u1/u2/u3 -> S regions with chunk rotation: LDS slot Sl holds chunk
    // (px = Sl>>5, s = ((Sl&31) - px) & 31) of that px's 512-B vector.
    auto dmaU = [&]() {
#pragma unroll
        for (int m = 0; m < 4; ++m) {   // u1: 2048 chunks, 4 instr/wave
            const int Sl = (wav * 4 + m) * 64 + lane;
            const int px = Sl >> 5;
            const int so = ((Sl & 31) - px) & 31;
            const int lr = px >> 3, lc = px & 7;
            dma16(u1 + ((size_t)(b * 1600 + (8 * R + lr) * 40 + 8 * C + lc)) * CCH + so * 8,
                  S1c + (wav * 4 + m) * 512);
        }
        {                               // u2: 512 chunks, 1 instr/wave
            const int Sl = wav * 64 + lane;
            const int px = Sl >> 5;
            const int so = ((Sl & 31) - px) & 31;
            const int lr = px >> 2, lc = px & 3;
            dma16(u2 + ((size_t)(b * 400 + (4 * R + lr) * 20 + 4 * C + lc)) * CCH + so * 8,
                  S2c + wav * 512);
        }
        if (wav < 2) {                  // u3: 128 chunks, waves 0-1
            const int Sl = wav * 64 + lane;
            const int px = Sl >> 5;
            const int so = ((Sl & 31) - px) & 31;
            const int lr = px >> 1, lc = px & 1;
            dma16(u3 + ((size_t)(b * 100 + (2 * R + lr) * 10 + 2 * C + lc)) * CCH + so * 8,
                  S3c + wav * 512);
        }
    };

    float4_ accA[16], accB[16];
#pragma unroll
    for (int i = 0; i < 16; ++i) {
        accA[i] = (float4_){0.f, 0.f, 0.f, 0.f};
        accB[i] = (float4_){0.f, 0.f, 0.f, 0.f};
    }

    const int pxA = wav * 32 + ln;     // fine row 2w, col ln
    const int pxB = pxA + 16;          // fine row 2w+1
    const int rotA = (pxA + 8 * quad) & 255;   // rotated F-slot (loop-invariant)
    const int rotB = (pxB + 8 * quad) & 255;

    // Prologue: u-DMA first (oldest -> drained by iter<=1's vmcnt, rides under
    // the K-loop), then 2-deep K pipeline D(0)->buf0, D(1)->buf1.
    dmaU();
    dmaW(0, 0); dmaF(0, 0);
    dmaW(1, 1); dmaF(1, 1);
#pragma unroll
    for (int ks = 0; ks < 8; ++ks) {
        // Wait for D(ks) (6 newer loads of D(ks+1) stay in flight); barrier
        // publishes every wave's D(ks) landing. Never a full drain except last.
        if (ks < 7) asm volatile("s_waitcnt vmcnt(6)" ::: "memory");
        else        asm volatile("s_waitcnt vmcnt(0)" ::: "memory");
        __builtin_amdgcn_s_barrier();

        const short* Wl = (ks & 1) ? Wb1 : Wb0;
        const float* Fl = (ks & 1) ? Fb1 : Fb0;
        short8 bfA, bfB;
#pragma unroll
        for (int j = 0; j < 8; ++j) {
            bfA[j] = f2bf(Fl[(quad * 8 + j) * 256 + rotA]);
            bfB[j] = f2bf(Fl[(quad * 8 + j) * 256 + rotB]);
        }
#pragma unroll
        for (int mt = 0; mt < 16; ++mt) {
            short8 afrag = *(const short8*)(Wl + mt * 512 + lane * 8);   // shared A
            accA[mt] = __builtin_amdgcn_mfma_f32_16x16x32_bf16(afrag, bfA, accA[mt], 0, 0, 0);
            accB[mt] = __builtin_amdgcn_mfma_f32_16x16x32_bf16(afrag, bfB, accB[mt], 0, 0, 0);
        }

        if (ks < 6) {
            // All waves done reading buf (ks&1) -> safe to overwrite with D(ks+2).
            asm volatile("s_waitcnt lgkmcnt(0)" ::: "memory");
            __builtin_amdgcn_s_barrier();
            dmaW(ks + 2, ks & 1); dmaF(ks + 2, ks & 1);
        }
    }

    // Bias + per-pixel norm. C/D layout (validated): col(px)=lane&15, row(ch)=quad*4+r.
    float ssA = 0.f, ssB = 0.f;
#pragma unroll
    for (int mt = 0; mt < 16; ++mt) {
        float4_ bv = *(const float4_*)(bias + mt * 16 + quad * 4);
#pragma unroll
        for (int r = 0; r < 4; ++r) {
            float vA = accA[mt][r] + bv[r]; accA[mt][r] = vA; ssA += vA * vA;
            float vB = accB[mt][r] + bv[r]; accB[mt][r] = vB; ssB += vB * vB;
        }
    }
    ssA += __shfl_xor(ssA, 16); ssA += __shfl_xor(ssA, 32);
    ssB += __shfl_xor(ssB, 16); ssB += __shfl_xor(ssB, 32);
    const float invA = 1.f / sqrtf(fmaxf(ssA, 1e-24f));
    const float invB = 1.f / sqrtf(fmaxf(ssB, 1e-24f));

    // S regions were DMA'd in the prologue and published by the K-loop's own
    // barriers (u-DMAs forced complete by iter 1's vmcnt(6)). No extra barrier.
    // Fine dots. pxA row = 2w, pxB row = 2w+1 -> identical coarse parents:
    const int c1l = wav * 8 + (ln >> 1);
    const int c2l = (wav >> 1) * 4 + (ln >> 2);
    const int c3l = (wav >> 2) * 2 + (ln >> 3);
    float d01 = 0.f, d02 = 0.f, d03 = 0.f;
#pragma unroll
    for (int mt = 0; mt < 16; ++mt) {
        const int so = 2 * mt + (quad >> 1);   // 16B-chunk index of ch range
        const int hf = (quad & 1) * 4;         // 8B half within chunk (shorts)
        short4_ v1 = *(const short4_*)(&S1c[c1l * 256 + ((so + c1l) & 31) * 8 + hf]);
        short4_ v2 = *(const short4_*)(&S2c[c2l * 256 + ((so + c2l) & 31) * 8 + hf]);
        short4_ v3 = *(const short4_*)(&S3c[c3l * 256 + ((so + c3l) & 31) * 8 + hf]);
#pragma unroll
        for (int r = 0; r < 4; ++r) {
            float s = accA[mt][r] * invA + accB[mt][r] * invB;
            d01 += s * bf2f(v1[r]);
            d02 += s * bf2f(v2[r]);
            d03 += s * bf2f(v3[r]);
        }
    }
    {
        float vals[3] = {d01, d02, d03};
#pragma unroll
        for (int p = 0; p < 3; ++p) {
            float v = vals[p];
            v += __shfl_xor(v, 1);  v += __shfl_xor(v, 2);  v += __shfl_xor(v, 4);
            v += __shfl_xor(v, 8);  v += __shfl_xor(v, 16); v += __shfl_xor(v, 32);
            if (lane == 0) redF[wav * 3 + p] = v;
        }
    }

    // Coarse dots, chunk index so = 2k + (q>>1), half = q&1 (rotation swizzle).
    if (wav < 4) {   // d12/d13 per u1 px: 64 px, 4 lanes each, 64 ch per lane
        const int p1 = wav * 16 + (lane >> 2);   // 0..63
        const int q  = lane & 3;
        const int lr = p1 >> 3, lc = p1 & 7;
        const int par2 = (lr >> 1) * 4 + (lc >> 1);
        const int par3 = (lr >> 2) * 2 + (lc >> 2);
        float e12 = 0.f, e13 = 0.f;
#pragma unroll
        for (int k = 0; k < 16; ++k) {
            const int so = 2 * k + (q >> 1);
            const int hf = (q & 1) * 4;
            short4_ a1 = *(const short4_*)(&S1c[p1 * 256 + ((so + p1) & 31) * 8 + hf]);
            short4_ a2 = *(const short4_*)(&S2c[par2 * 256 + ((so + par2) & 31) * 8 + hf]);
            short4_ a3 = *(const short4_*)(&S3c[par3 * 256 + ((so + par3) & 31) * 8 + hf]);
#pragma unroll
            for (int r = 0; r < 4; ++r) {
                float x1 = bf2f(a1[r]);
                e12 += x1 * bf2f(a2[r]);
                e13 += x1 * bf2f(a3[r]);
            }
        }
        float ev[2] = {e12, e13};
#pragma unroll
        for (int p = 0; p < 2; ++p) {
            float v = ev[p];
            v += __shfl_xor(v, 1);  v += __shfl_xor(v, 2);  v += __shfl_xor(v, 4);
            v += __shfl_xor(v, 8);  v += __shfl_xor(v, 16); v += __shfl_xor(v, 32);
            if (lane == 0) redC[wav * 2 + p] = v;
        }
    } else if (wav == 4) {   // d23 per u2 px (16 px, 4 lanes each = full wave)
        const int p2 = lane >> 2;
        const int q  = lane & 3;
        const int lr = p2 >> 2, lc = p2 & 3;
        const int par3 = (lr >> 1) * 2 + (lc >> 1);
        float e23 = 0.f;
#pragma unroll
        for (int k = 0; k < 16; ++k) {
            const int so = 2 * k + (q >> 1);
            const int hf = (q & 1) * 4;
            short4_ a2 = *(const short4_*)(&S2c[p2 * 256 + ((so + p2) & 31) * 8 + hf]);
            short4_ a3 = *(const short4_*)(&S3c[par3 * 256 + ((so + par3) & 31) * 8 + hf]);
#pragma unroll
            for (int r = 0; r < 4; ++r) e23 += bf2f(a2[r]) * bf2f(a3[r]);
        }
        e23 += __shfl_xor(e23, 1);  e23 += __shfl_xor(e23, 2);  e23 += __shfl_xor(e23, 4);
        e23 += __shfl_xor(e23, 8);  e23 += __shfl_xor(e23, 16); e23 += __shfl_xor(e23, 32);
        if (lane == 0) redC[8] = e23;
    }
    __syncthreads();

    if (t < 6) {
        float v;
        if (t < 3) {
            v = 0.f;
#pragma unroll
            for (int w = 0; w < 8; ++w) v += redF[w * 3 + t];
        } else if (t == 3) v = redC[0] + redC[2] + redC[4] + redC[6];   // d12
        else if (t == 4)   v = redC[1] + redC[3] + redC[5] + redC[7];   // d13
        else               v = redC[8];                                 // d23
        partial[((size_t)b * 6 + t) * 25 + c] = v;
    }
}

// ---------- Softmax over j for each (b,i) row (sums 25 cell partials) ----------
__global__ void softmax4(const float* __restrict__ partial, float* __restrict__ out) {
    int t = threadIdx.x;
    if (t >= 128) return;
    int b = t >> 4, i = (t >> 2) & 3, j = t & 3;
    float a[4];
#pragma unroll
    for (int jj = 0; jj < 4; ++jj) {
        if (jj == i) { a[jj] = 1.0f; continue; }
        int lo = i < jj ? i : jj;
        int hi = i < jj ? jj : i;
        int pidx;
        if (lo == 0) pidx = hi - 1;          // (0,1)=0 (0,2)=1 (0,3)=2
        else if (lo == 1) pidx = 1 + hi;     // (1,2)=3 (1,3)=4
        else pidx = 5;                       // (2,3)=5
        const float* pp = partial + ((size_t)b * 6 + pidx) * 25;
        float s = 0.f;
        for (int k = 0; k < 25; ++k) s += pp[k];
        int rf = 80 >> lo;
        a[jj] = s / (float)(rf * rf);
    }
    float m = fmaxf(fmaxf(a[0], a[1]), fmaxf(a[2], a[3]));
    float e0 = expf(a[0] - m), e1 = expf(a[1] - m), e2 = expf(a[2] - m), e3 = expf(a[3] - m);
    float sum = e0 + e1 + e2 + e3;
    float ev = (j == 0) ? e0 : (j == 1) ? e1 : (j == 2) ? e2 : e3;
    out[t] = ev / sum;
}

extern "C" void kernel_launch(void* const* d_in, const int* in_sizes, int n_in,
                              void* d_out, int out_size, void* d_ws, size_t ws_size,
                              hipStream_t stream) {
    // setup_inputs dict insertion order: f0,w0,b0, f1,w1,b1, f2,w2,b2, f3,w3,b3
    const float* f[4]  = {(const float*)d_in[0], (const float*)d_in[3],
                          (const float*)d_in[6], (const float*)d_in[9]};
    const float* w[4]  = {(const float*)d_in[1], (const float*)d_in[4],
                          (const float*)d_in[7], (const float*)d_in[10]};
    const float* bs[4] = {(const float*)d_in[2], (const float*)d_in[5],
                          (const float*)d_in[8], (const float*)d_in[11]};

    char* ws = (char*)d_ws;
    size_t off = 0;
    short* u1 = (short*)(ws + off); off += (size_t)8 * CCH * 1600 * sizeof(short);
    short* u2 = (short*)(ws + off); off += (size_t)8 * CCH * 400  * sizeof(short);
    short* u3 = (short*)(ws + off); off += (size_t)8 * CCH * 100  * sizeof(short);
    short* wp = (short*)(ws + off); off += (size_t)65536 * sizeof(short);
    float* partial = (float*)(ws + off);   // 8*6*25 floats

    static int smax_set = 0;
    if (!smax_set) {
        hipFuncSetAttribute(reinterpret_cast<const void*>(proj0_dots),
                            hipFuncAttributeMaxDynamicSharedMemorySize, 141568);
        smax_set = 1;
    }

    proj_small<<<304, 256, 0, stream>>>(f[1], f[2], f[3],
                                        w[0], w[1], w[2], w[3],
                                        bs[1], bs[2], bs[3],
                                        u1, u2, u3, wp);

    proj0_dots<<<dim3(25, 8), 512, 141568, stream>>>(f[0], wp, bs[0],
                                                     u1, u2, u3, partial);

    softmax4<<<1, 128, 0, stream>>>(partial, (float*)d_out);
}

// Round 5
// 143.083 us; speedup vs baseline: 1.0288x; 1.0288x over previous
//
#include <hip/hip_runtime.h>

// EdgeAttention round 13:
//  - pd REVERTED to r11 exactly (measured best 145.9; r12's swizzle+u-prologue
//    was neutral-to-negative -> dropped).
//  - NEW pack_w kernel: packs w0..w3 fp32->bf16 fragment-linear ONCE (was: w0
//    packed by ps side-blocks, w1..w3 re-converted per block per iter).
//  - proj_small restructured to the r11-validated counted-vmcnt DMA pipeline:
//    W (4 instr/wave) + F (2 instr/wave) global_load_lds into 48 KB dbuf LDS,
//    vmcnt(6) + raw s_barrier, D(k+2) after lgkmcnt(0)+barrier. Per-iter VALU
//    drops from ~40 f2bf + 9 ds_write to 8 f2bf. Edge tiles (f2/f3): per-lane
//    global px chunk clamped to L-4 (dup values -> discarded output columns).

#define CCH 256

typedef __attribute__((ext_vector_type(8))) short short8;
typedef __attribute__((ext_vector_type(4))) short short4_;
typedef __attribute__((ext_vector_type(4))) float float4_;

__device__ inline short f2bf(float x) {
    union { float f; unsigned u; } c; c.f = x;
    unsigned u = c.u + 0x7FFFu + ((c.u >> 16) & 1u);
    return (short)(u >> 16);
}
__device__ inline float bf2f(short b) {
    union { unsigned u; float f; } c; c.u = ((unsigned)(unsigned short)b) << 16;
    return c.f;
}

__device__ inline void dma16(const void* g, void* l) {
    __builtin_amdgcn_global_load_lds(
        (const __attribute__((address_space(1))) void*)g,
        (__attribute__((address_space(3))) void*)l, 16, 0, 0);
}

// ---------- pack_w: w0..w3 fp32 -> bf16 fragment-linear ----------
// Layout (per matrix, 65536 shorts): pos = ks*8192 + mt*512 + lane*8 + e, where
// short = w[(mt*16 + (lane&15))*256 + ks*32 + (lane>>4)*8 + e]. Matches the
// MFMA A-fragment read afrag = Wl[mt*512 + lane*8] used by ps and pd.
__global__ __launch_bounds__(256) void pack_w(
    const float* __restrict__ w0, const float* __restrict__ w1,
    const float* __restrict__ w2, const float* __restrict__ w3,
    short* __restrict__ wp)
{
    int id = blockIdx.x * 256 + threadIdx.x;     // 0..32767 short8s
    int mtx = id >> 13;
    const float* w = (mtx == 0) ? w0 : (mtx == 1) ? w1 : (mtx == 2) ? w2 : w3;
    int rest = id & 8191;
    int ks = rest >> 10;
    int r2 = rest & 1023;
    int mt = r2 >> 6;
    int fl = r2 & 63;
    int ln = fl & 15, qd = fl >> 4;
    const float* src = w + (size_t)(mt * 16 + ln) * CCH + ks * 32 + qd * 8;
    short8 v;
#pragma unroll
    for (int j = 0; j < 8; ++j) v[j] = f2bf(src[j]);
    *(short8*)(wp + (size_t)id * 8) = v;
}

// ---------- proj_small v2: counted-vmcnt DMA pipeline (pd-r11 skeleton) ------
// 272 blocks, 4 waves. Block -> (scale, b, 64-px tile). Wave w owns px w*16+ln.
// LDS: W dbuf 2x16KB (fragment-linear bf16) + F dbuf 2x8KB ([32ch][64px] fp32).
__global__ __launch_bounds__(256) void proj_small(
    const float* __restrict__ f1, const float* __restrict__ f2,
    const float* __restrict__ f3, const short* __restrict__ wp,
    const float* __restrict__ b1, const float* __restrict__ b2,
    const float* __restrict__ b3,
    short* __restrict__ u1, short* __restrict__ u2, short* __restrict__ u3)
{
    __shared__ __align__(16) short Wt0[16 * 512];   // 16 KB
    __shared__ __align__(16) short Wt1[16 * 512];
    __shared__ __align__(16) float Ft0[32 * 64];    //  8 KB
    __shared__ __align__(16) float Ft1[32 * 64];

    const int blk = blockIdx.x;
    const int t = threadIdx.x;

    int b, tile, L, sidx;
    const float* F; const float* bias; short* U;
    if (blk < 200)      { int r = blk;       b = r / 25; tile = r % 25; L = 1600; F = f1; bias = b1; U = u1; sidx = 1; }
    else if (blk < 256) { int r = blk - 200; b = r / 7;  tile = r % 7;  L = 400;  F = f2; bias = b2; U = u2; sidx = 2; }
    else                { int r = blk - 256; b = r / 2;  tile = r % 2;  L = 100;  F = f3; bias = b3; U = u3; sidx = 3; }

    const int lane = t & 63;
    const int wav  = t >> 6;           // 0..3
    const int ln   = lane & 15;
    const int quad = lane >> 4;
    const int pixbase = tile * 64;
    const float* Fb = F + (size_t)b * CCH * L;
    const short* wps = wp + (size_t)sidx * 65536;

    // Per-lane F source px chunk (clamped to stay in-buffer on edge tiles).
    int gp = pixbase + (lane & 15) * 4;
    if (gp > L - 4) gp = L - 4;
    const int chq = lane >> 4;         // ch offset within 4-ch group

    auto dmaW = [&](int ks, int buf) {             // 4 instr/wave (16 KB total)
        short* Wb = buf ? Wt1 : Wt0;
#pragma unroll
        for (int m = 0; m < 4; ++m) {
            const int k = wav * 4 + m;                      // mt 0..15
            dma16(wps + (size_t)ks * 8192 + k * 512 + lane * 8, Wb + k * 512);
        }
    };
    auto dmaF = [&](int ks, int buf) {             // 2 instr/wave (8 KB total)
        float* Fb_l = buf ? Ft1 : Ft0;
#pragma unroll
        for (int m = 0; m < 2; ++m) {
            const int k4 = wav * 2 + m;                     // 4-ch group 0..7
            const int ch = k4 * 4 + chq;
            dma16(Fb + (size_t)(ks * 32 + ch) * L + gp, Fb_l + k4 * 256);
        }
    };

    float4_ acc[16];
#pragma unroll
    for (int i = 0; i < 16; ++i) acc[i] = (float4_){0.f, 0.f, 0.f, 0.f};

    const int fpx = wav * 16 + ln;     // this lane's pixel 0..63

    dmaW(0, 0); dmaF(0, 0);
    dmaW(1, 1); dmaF(1, 1);
#pragma unroll
    for (int ks = 0; ks < 8; ++ks) {
        if (ks < 7) asm volatile("s_waitcnt vmcnt(6)" ::: "memory");
        else        asm volatile("s_waitcnt vmcnt(0)" ::: "memory");
        __builtin_amdgcn_s_barrier();

        const short* Wl = (ks & 1) ? Wt1 : Wt0;
        const float* Fl = (ks & 1) ? Ft1 : Ft0;
        short8 bfrag;
#pragma unroll
        for (int j = 0; j < 8; ++j)
            bfrag[j] = f2bf(Fl[(quad * 8 + j) * 64 + fpx]);
#pragma unroll
        for (int mt = 0; mt < 16; ++mt) {
            short8 afrag = *(const short8*)(Wl + mt * 512 + lane * 8);
            acc[mt] = __builtin_amdgcn_mfma_f32_16x16x32_bf16(afrag, bfrag, acc[mt], 0, 0, 0);
        }

        if (ks < 6) {
            asm volatile("s_waitcnt lgkmcnt(0)" ::: "memory");
            __builtin_amdgcn_s_barrier();
            dmaW(ks + 2, ks & 1); dmaF(ks + 2, ks & 1);
        }
    }

    float ss = 0.f;
#pragma unroll
    for (int mt = 0; mt < 16; ++mt) {
        float4_ bv = *(const float4_*)(bias + mt * 16 + quad * 4);
#pragma unroll
        for (int r = 0; r < 4; ++r) { float v = acc[mt][r] + bv[r]; acc[mt][r] = v; ss += v * v; }
    }
    ss += __shfl_xor(ss, 16);
    ss += __shfl_xor(ss, 32);
    const float inv = 1.f / sqrtf(fmaxf(ss, 1e-24f));

    const int gpixw = pixbase + fpx;
    if (gpixw < L) {
        short* dst = U + ((size_t)b * L + gpixw) * CCH;
#pragma unroll
        for (int mt = 0; mt < 16; ++mt) {
            short4_ v;
#pragma unroll
            for (int r = 0; r < 4; ++r) v[r] = f2bf(acc[mt][r] * inv);
            *(short4_*)(dst + mt * 16 + quad * 4) = v;
        }
    }
}

// ---------- proj0_dots (r11 verbatim): 256-px tile, counted-vmcnt pipeline ------
#define SPITCH 264  // epilogue staging pitch: 528 B row stride, bank-spread
__global__ __launch_bounds__(512, 2) void proj0_dots(
    const float* __restrict__ F, const short* __restrict__ wp,
    const float* __restrict__ bias,
    const short* __restrict__ u1, const short* __restrict__ u2,
    const short* __restrict__ u3,
    float* __restrict__ partial)
{
    extern __shared__ __align__(16) char smem[];     // 98304 B dynamic
    short* Wb0 = (short*)smem;                    // 16 KB bf16 W slice, buf 0
    short* Wb1 = (short*)(smem + 16384);          // buf 1
    float* Fb0 = (float*)(smem + 32768);          // 32 KB fp32 F slice [32ch][256px]
    float* Fb1 = (float*)(smem + 65536);          // buf 1 (ends at 98304)
    short* S1 = (short*)smem;                     // 64 px * 264 * 2 = 33792 B
    short* S2 = (short*)(smem + 33792);           // 16 px           =  8448 B
    short* S3 = (short*)(smem + 42240);           //  4 px           =  2112 B
    float* redF = (float*)(smem + 44352);         // [8][3]
    float* redC = (float*)(smem + 44448);         // [9]

    const int c  = blockIdx.x;         // 0..24
    const int b  = blockIdx.y;
    const int R  = c / 5, C = c - R * 5;
    const int t  = threadIdx.x;
    const int lane = t & 63;
    const int wav  = t >> 6;           // 0..7
    const int ln   = lane & 15;
    const int quad = lane >> 4;
    const float* Fbase = F + (size_t)b * CCH * 6400;

    auto dmaW = [&](int ks, int buf) {             // 2 instr/wave (16 KB total)
        short* Wb = buf ? Wb1 : Wb0;
#pragma unroll
        for (int m = 0; m < 2; ++m) {
            const int k = wav * 2 + m;                      // 0..15
            dma16(wp + (size_t)ks * 8192 + k * 512 + lane * 8, Wb + k * 512);
        }
    };
    auto dmaF = [&](int ks, int buf) {             // 4 instr/wave (32 KB total)
        float* Fb = buf ? Fb1 : Fb0;
        const int gpx = (16 * R + (lane >> 2)) * 80 + 16 * C + (lane & 3) * 4;
#pragma unroll
        for (int m = 0; m < 4; ++m) {
            const int k = wav * 4 + m;                      // channel 0..31
            dma16(Fbase + (size_t)(ks * 32 + k) * 6400 + gpx, Fb + k * 256);
        }
    };

    float4_ accA[16], accB[16];
#pragma unroll
    for (int i = 0; i < 16; ++i) {
        accA[i] = (float4_){0.f, 0.f, 0.f, 0.f};
        accB[i] = (float4_){0.f, 0.f, 0.f, 0.f};
    }

    const int pxA = wav * 32 + ln;     // fine row 2w, col ln
    const int pxB = pxA + 16;          // fine row 2w+1

    dmaW(0, 0); dmaF(0, 0);
    dmaW(1, 1); dmaF(1, 1);
#pragma unroll
    for (int ks = 0; ks < 8; ++ks) {
        if (ks < 7) asm volatile("s_waitcnt vmcnt(6)" ::: "memory");
        else        asm volatile("s_waitcnt vmcnt(0)" ::: "memory");
        __builtin_amdgcn_s_barrier();

        const short* Wl = (ks & 1) ? Wb1 : Wb0;
        const float* Fl = (ks & 1) ? Fb1 : Fb0;
        short8 bfA, bfB;
#pragma unroll
        for (int j = 0; j < 8; ++j) {
            bfA[j] = f2bf(Fl[(quad * 8 + j) * 256 + pxA]);
            bfB[j] = f2bf(Fl[(quad * 8 + j) * 256 + pxB]);
        }
#pragma unroll
        for (int mt = 0; mt < 16; ++mt) {
            short8 afrag = *(const short8*)(Wl + mt * 512 + lane * 8);   // shared A
            accA[mt] = __builtin_amdgcn_mfma_f32_16x16x32_bf16(afrag, bfA, accA[mt], 0, 0, 0);
            accB[mt] = __builtin_amdgcn_mfma_f32_16x16x32_bf16(afrag, bfB, accB[mt], 0, 0, 0);
        }

        if (ks < 6) {
            asm volatile("s_waitcnt lgkmcnt(0)" ::: "memory");
            __builtin_amdgcn_s_barrier();
            dmaW(ks + 2, ks & 1); dmaF(ks + 2, ks & 1);
        }
    }

    float ssA = 0.f, ssB = 0.f;
#pragma unroll
    for (int mt = 0; mt < 16; ++mt) {
        float4_ bv = *(const float4_*)(bias + mt * 16 + quad * 4);
#pragma unroll
        for (int r = 0; r < 4; ++r) {
            float vA = accA[mt][r] + bv[r]; accA[mt][r] = vA; ssA += vA * vA;
            float vB = accB[mt][r] + bv[r]; accB[mt][r] = vB; ssB += vB * vB;
        }
    }
    ssA += __shfl_xor(ssA, 16); ssA += __shfl_xor(ssA, 32);
    ssB += __shfl_xor(ssB, 16); ssB += __shfl_xor(ssB, 32);
    const float invA = 1.f / sqrtf(fmaxf(ssA, 1e-24f));
    const float invB = 1.f / sqrtf(fmaxf(ssB, 1e-24f));

    __syncthreads();   // S1/S2/S3 alias the K-loop buffers (vmcnt already 0)

    {   // u1: 64 px (8 rows x 8 cols)
        const int p1 = t >> 3, co = (t & 7) * 32;
        const int lr = p1 >> 3, lc = p1 & 7;
        const short* src = u1 + ((size_t)(b * 1600 + (8 * R + lr) * 40 + 8 * C + lc)) * CCH + co;
        short* dst = S1 + p1 * SPITCH + co;
#pragma unroll
        for (int j = 0; j < 4; ++j) *(short8*)(dst + j * 8) = *(const short8*)(src + j * 8);
    }
    if (t < 128) {   // u2: 16 px (4 rows x 4 cols)
        const int p2 = t >> 3, co = (t & 7) * 32;
        const int lr = p2 >> 2, lc = p2 & 3;
        const short* src = u2 + ((size_t)(b * 400 + (4 * R + lr) * 20 + 4 * C + lc)) * CCH + co;
        short* dst = S2 + p2 * SPITCH + co;
#pragma unroll
        for (int j = 0; j < 4; ++j) *(short8*)(dst + j * 8) = *(const short8*)(src + j * 8);
    }
    if (t < 32) {    // u3: 4 px (2 rows x 2 cols)
        const int p3 = t >> 3, co = (t & 7) * 32;
        const int lr = p3 >> 1, lc = p3 & 1;
        const short* src = u3 + ((size_t)(b * 100 + (2 * R + lr) * 10 + 2 * C + lc)) * CCH + co;
        short* dst = S3 + p3 * SPITCH + co;
#pragma unroll
        for (int j = 0; j < 4; ++j) *(short8*)(dst + j * 8) = *(const short8*)(src + j * 8);
    }
    __syncthreads();

    const int c1l = wav * 8 + (ln >> 1);
    const int c2l = (wav >> 1) * 4 + (ln >> 2);
    const int c3l = (wav >> 2) * 2 + (ln >> 3);
    float d01 = 0.f, d02 = 0.f, d03 = 0.f;
#pragma unroll
    for (int mt = 0; mt < 16; ++mt) {
        const int ch = mt * 16 + quad * 4;
        short4_ v1 = *(const short4_*)(&S1[c1l * SPITCH + ch]);
        short4_ v2 = *(const short4_*)(&S2[c2l * SPITCH + ch]);
        short4_ v3 = *(const short4_*)(&S3[c3l * SPITCH + ch]);
#pragma unroll
        for (int r = 0; r < 4; ++r) {
            float s = accA[mt][r] * invA + accB[mt][r] * invB;
            d01 += s * bf2f(v1[r]);
            d02 += s * bf2f(v2[r]);
            d03 += s * bf2f(v3[r]);
        }
    }
    {
        float vals[3] = {d01, d02, d03};
#pragma unroll
        for (int p = 0; p < 3; ++p) {
            float v = vals[p];
            v += __shfl_xor(v, 1);  v += __shfl_xor(v, 2);  v += __shfl_xor(v, 4);
            v += __shfl_xor(v, 8);  v += __shfl_xor(v, 16); v += __shfl_xor(v, 32);
            if (lane == 0) redF[wav * 3 + p] = v;
        }
    }

    if (wav < 4) {   // d12/d13 per u1 px: 64 px, 4 lanes each, 64 ch per lane
        const int p1 = wav * 16 + (lane >> 2);   // 0..63
        const int q  = lane & 3;
        const int lr = p1 >> 3, lc = p1 & 7;
        const int par2 = (lr >> 1) * 4 + (lc >> 1);
        const int par3 = (lr >> 2) * 2 + (lc >> 2);
        float e12 = 0.f, e13 = 0.f;
#pragma unroll
        for (int k = 0; k < 16; ++k) {
            const int co = k * 16 + q * 4;
            short4_ a1 = *(const short4_*)(&S1[p1 * SPITCH + co]);
            short4_ a2 = *(const short4_*)(&S2[par2 * SPITCH + co]);
            short4_ a3 = *(const short4_*)(&S3[par3 * SPITCH + co]);
#pragma unroll
            for (int r = 0; r < 4; ++r) {
                float x1 = bf2f(a1[r]);
                e12 += x1 * bf2f(a2[r]);
                e13 += x1 * bf2f(a3[r]);
            }
        }
        float ev[2] = {e12, e13};
#pragma unroll
        for (int p = 0; p < 2; ++p) {
            float v = ev[p];
            v += __shfl_xor(v, 1);  v += __shfl_xor(v, 2);  v += __shfl_xor(v, 4);
            v += __shfl_xor(v, 8);  v += __shfl_xor(v, 16); v += __shfl_xor(v, 32);
            if (lane == 0) redC[wav * 2 + p] = v;
        }
    } else if (wav == 4) {   // d23 per u2 px (16 px, 4 lanes each = full wave)
        const int p2 = lane >> 2;
        const int q  = lane & 3;
        const int lr = p2 >> 2, lc = p2 & 3;
        const int par3 = (lr >> 1) * 2 + (lc >> 1);
        float e23 = 0.f;
#pragma unroll
        for (int k = 0; k < 16; ++k) {
            const int co = k * 16 + q * 4;
            short4_ a2 = *(const short4_*)(&S2[p2 * SPITCH + co]);
            short4_ a3 = *(const short4_*)(&S3[par3 * SPITCH + co]);
#pragma unroll
            for (int r = 0; r < 4; ++r) e23 += bf2f(a2[r]) * bf2f(a3[r]);
        }
        e23 += __shfl_xor(e23, 1);  e23 += __shfl_xor(e23, 2);  e23 += __shfl_xor(e23, 4);
        e23 += __shfl_xor(e23, 8);  e23 += __shfl_xor(e23, 16); e23 += __shfl_xor(e23, 32);
        if (lane == 0) redC[8] = e23;
    }
    __syncthreads();

    if (t < 6) {
        float v;
        if (t < 3) {
            v = 0.f;
#pragma unroll
            for (int w = 0; w < 8; ++w) v += redF[w * 3 + t];
        } else if (t == 3) v = redC[0] + redC[2] + redC[4] + redC[6];   // d12
        else if (t == 4)   v = redC[1] + redC[3] + redC[5] + redC[7];   // d13
        else               v = redC[8];                                 // d23
        partial[((size_t)b * 6 + t) * 25 + c] = v;
    }
}

// ---------- Softmax over j for each (b,i) row (sums 25 cell partials) ----------
__global__ void softmax4(const float* __restrict__ partial, float* __restrict__ out) {
    int t = threadIdx.x;
    if (t >= 128) return;
    int b = t >> 4, i = (t >> 2) & 3, j = t & 3;
    float a[4];
#pragma unroll
    for (int jj = 0; jj < 4; ++jj) {
        if (jj == i) { a[jj] = 1.0f; continue; }
        int lo = i < jj ? i : jj;
        int hi = i < jj ? jj : i;
        int pidx;
        if (lo == 0) pidx = hi - 1;          // (0,1)=0 (0,2)=1 (0,3)=2
        else if (lo == 1) pidx = 1 + hi;     // (1,2)=3 (1,3)=4
        else pidx = 5;                       // (2,3)=5
        const float* pp = partial + ((size_t)b * 6 + pidx) * 25;
        float s = 0.f;
        for (int k = 0; k < 25; ++k) s += pp[k];
        int rf = 80 >> lo;
        a[jj] = s / (float)(rf * rf);
    }
    float m = fmaxf(fmaxf(a[0], a[1]), fmaxf(a[2], a[3]));
    float e0 = expf(a[0] - m), e1 = expf(a[1] - m), e2 = expf(a[2] - m), e3 = expf(a[3] - m);
    float sum = e0 + e1 + e2 + e3;
    float ev = (j == 0) ? e0 : (j == 1) ? e1 : (j == 2) ? e2 : e3;
    out[t] = ev / sum;
}

extern "C" void kernel_launch(void* const* d_in, const int* in_sizes, int n_in,
                              void* d_out, int out_size, void* d_ws, size_t ws_size,
                              hipStream_t stream) {
    // setup_inputs dict insertion order: f0,w0,b0, f1,w1,b1, f2,w2,b2, f3,w3,b3
    const float* f[4]  = {(const float*)d_in[0], (const float*)d_in[3],
                          (const float*)d_in[6], (const float*)d_in[9]};
    const float* w[4]  = {(const float*)d_in[1], (const float*)d_in[4],
                          (const float*)d_in[7], (const float*)d_in[10]};
    const float* bs[4] = {(const float*)d_in[2], (const float*)d_in[5],
                          (const float*)d_in[8], (const float*)d_in[11]};

    char* ws = (char*)d_ws;
    size_t off = 0;
    short* u1 = (short*)(ws + off); off += (size_t)8 * CCH * 1600 * sizeof(short);
    short* u2 = (short*)(ws + off); off += (size_t)8 * CCH * 400  * sizeof(short);
    short* u3 = (short*)(ws + off); off += (size_t)8 * CCH * 100  * sizeof(short);
    short* wp = (short*)(ws + off); off += (size_t)4 * 65536 * sizeof(short);  // w0..w3 packed
    float* partial = (float*)(ws + off);   // 8*6*25 floats

    static int smax_set = 0;
    if (!smax_set) {
        hipFuncSetAttribute(reinterpret_cast<const void*>(proj0_dots),
                            hipFuncAttributeMaxDynamicSharedMemorySize, 98304);
        smax_set = 1;
    }

    pack_w<<<128, 256, 0, stream>>>(w[0], w[1], w[2], w[3], wp);

    proj_small<<<272, 256, 0, stream>>>(f[1], f[2], f[3], wp,
                                        bs[1], bs[2], bs[3],
                                        u1, u2, u3);

    proj0_dots<<<dim3(25, 8), 512, 98304, stream>>>(f[0], wp, bs[0],
                                                    u1, u2, u3, partial);

    softmax4<<<1, 128, 0, stream>>>(partial, (float*)d_out);
}